// Round 11
// baseline (6188.377 us; speedup 1.0000x reference)
//
#include <hip/hip_runtime.h>

// ---------------------------------------------------------------------------
// StackedBidirectionalLstm  (B=32, T=512, IN=512, H=512, LAYERS=2, bidir, highway)
//
// Round 11: fuse fwd+bwd chains into one WG (64 WGs x 512 thr = 4 batch-
// quarters x 16 members; each WG runs BOTH directions, phase-alternated).
// Each direction's MALL exchange RTT hides under the other direction's
// compute phase. Exchange protocol identical to passing rounds 6/9/10:
// 16B chunks {6 bf16 | enc(s)} via sc0 sc1, poll-on-data with done-mask
// + s_sleep throttle. Weights register-resident per dir (2 x 80 VGPR).
// partF/partB single-buffered (barrier-separated); 2 barriers/iteration.
//
//   ws layout (bytes), total ~202.4 MiB:
//     px   @ 0          201,326,592  ([2][512*32][3072] bf16, t-major)
//     whp  @ 201326592   10,485,760  (packed Wh fragments)
//     hxc  @ 211812352      393,216  ([2 layer][2 buf][8 grp][16 m][8 r][6 c]x16B)
//   d_out scratch: phase A xbf/wxt0/wxt1, phase B a1bf (as previous rounds).
// ---------------------------------------------------------------------------

typedef float f32x4 __attribute__((ext_vector_type(4)));
typedef __bf16 bf16x8 __attribute__((ext_vector_type(8)));
typedef unsigned short us8 __attribute__((ext_vector_type(8)));
typedef unsigned short us4 __attribute__((ext_vector_type(4)));
typedef unsigned int u32x4 __attribute__((ext_vector_type(4)));

__device__ __forceinline__ unsigned short f2bf(float f) {
  unsigned int u = __float_as_uint(f);
  u += 0x7FFFu + ((u >> 16) & 1u);            // round-to-nearest-even
  return (unsigned short)(u >> 16);
}
__device__ __forceinline__ float bf2f(unsigned int h) {
  return __uint_as_float(h << 16);
}
__device__ __forceinline__ float sigf(float x) { return 1.0f / (1.0f + __expf(-x)); }
__device__ __forceinline__ float tanh_(float x) { return 2.0f / (1.0f + __expf(-2.0f * x)) - 1.0f; }

#define MFMA(a, b, c) __builtin_amdgcn_mfma_f32_16x16x32_bf16((a), (b), (c), 0, 0, 0)
#define GLOAD_LDS(gp, lp)                                                           \
  __builtin_amdgcn_global_load_lds(                                                 \
      (const __attribute__((address_space(1))) void*)(gp),                          \
      (__attribute__((address_space(3))) void*)(lp), 16, 0, 0)

// Coherent (device/system-scope) 16B pair load; no waitcnt inside.
__device__ __forceinline__ void chunk2_ld(const char* p, u32x4& a, u32x4& b) {
  asm volatile("global_load_dwordx4 %0, %2, off sc0 sc1\n\t"
               "global_load_dwordx4 %1, %2, off offset:16 sc0 sc1"
               : "=&v"(a), "=&v"(b) : "v"(p) : "memory");
}
// Fire-and-forget coherent 16B publish.
__device__ __forceinline__ void pub16(char* p, u32x4 v) {
  asm volatile("global_store_dwordx4 %0, %1, off sc0 sc1" :: "v"(p), "v"(v) : "memory");
}

// --------------------------- prep kernels ----------------------------------

__global__ void k_convert_x(const float* __restrict__ x, unsigned short* __restrict__ xb, int n4) {
  int i = blockIdx.x * blockDim.x + threadIdx.x;
  if (i < n4) {
    float4 v = ((const float4*)x)[i];
    us4 o;
    o[0] = f2bf(v.x); o[1] = f2bf(v.y); o[2] = f2bf(v.z); o[3] = f2bf(v.w);
    ((us4*)xb)[i] = o;
  }
}

// Tiled transpose: WxT[n][k] = bf16(Wx[k][n]); z = layer*2+dir
__global__ __launch_bounds__(256) void k_pack_wxT(
    const float* __restrict__ W0, const float* __restrict__ W1,
    const float* __restrict__ W2, const float* __restrict__ W3,
    unsigned short* __restrict__ o01, unsigned short* __restrict__ o23) {
  int y = blockIdx.z;
  int K = (y >> 1) ? 1024 : 512;
  int kb = blockIdx.y * 32;
  if (kb >= K) return;
  const float* W = (y == 0) ? W0 : (y == 1) ? W1 : (y == 2) ? W2 : W3;
  unsigned short* o = (y >> 1) ? (o23 + (size_t)(y & 1) * 3072 * 1024)
                               : (o01 + (size_t)(y & 1) * 3072 * 512);
  __shared__ float tile[32][33];
  int nb = blockIdx.x * 32;
  int tx = threadIdx.x & 31, ty = threadIdx.x >> 5;   // ty 0..7
#pragma unroll
  for (int r = 0; r < 4; ++r)
    tile[ty + r * 8][tx] = W[(size_t)(kb + ty + r * 8) * 3072 + nb + tx];
  __syncthreads();
#pragma unroll
  for (int r = 0; r < 4; ++r)
    o[(size_t)(nb + ty + r * 8) * K + kb + tx] = f2bf(tile[tx][ty + r * 8]);
}

// Pack Wh (512x2560 f32) into MFMA B-fragments:
// out[(((g*32+ns)*16+ks)*64+lane)*8+e] = Wh[ks*32+(lane>>4)*8+e][g*512+ns*16+(lane&15)]
__global__ void k_pack_whp(const float* __restrict__ W0, const float* __restrict__ W1,
                           const float* __restrict__ W2, const float* __restrict__ W3,
                           unsigned short* __restrict__ out) {
  int y = blockIdx.y;
  const float* W = (y == 0) ? W0 : (y == 1) ? W1 : (y == 2) ? W2 : W3;
  unsigned short* o = out + (size_t)y * 1310720;
  int v = blockIdx.x * 256 + threadIdx.x;   // < 163840
  int lane = v & 63, ks = (v >> 6) & 15, ns = (v >> 10) & 31, g = v >> 15;
  int col = g * 512 + ns * 16 + (lane & 15);
  int kb = ks * 32 + ((lane >> 4) << 3);
  us8 vec;
#pragma unroll
  for (int e = 0; e < 8; ++e) vec[e] = f2bf(W[(size_t)(kb + e) * 2560 + col]);
  *(us8*)&o[(size_t)v * 8] = vec;
}

// --------------------------- bf16 GEMM -------------------------------------
// px[rr][col] with rr = t*32+b (t-major), from A[16384][K] @ Bt[3072][K]^T.
__global__ __launch_bounds__(256) void k_gemm(const unsigned short* __restrict__ A,
                                              const unsigned short* __restrict__ BtBase,
                                              unsigned short* __restrict__ CBase, int K) {
  __shared__ __align__(128) unsigned short As[128 * 32];
  __shared__ __align__(128) unsigned short Bs[128 * 32];
  const unsigned short* Bt = BtBase + (size_t)blockIdx.z * 3072 * K;
  unsigned short* C = CBase + (size_t)blockIdx.z * 16384 * 3072;
  int tid = threadIdx.x;
  int w = tid >> 6, l = tid & 63;
  int m0 = blockIdx.x * 128, n0 = blockIdx.y * 128;
  int wr = (w >> 1) * 64, wc = (w & 1) * 64;
  f32x4 acc[4][4];
#pragma unroll
  for (int i = 0; i < 4; ++i)
#pragma unroll
    for (int j = 0; j < 4; ++j) acc[i][j] = (f32x4){0.f, 0.f, 0.f, 0.f};

  for (int k0 = 0; k0 < K; k0 += 32) {
    __syncthreads();
#pragma unroll
    for (int half = 0; half < 2; ++half) {
      int r = w * 32 + half * 16 + (l >> 2);     // row within tile
      int gq = (l & 3) ^ (r & 3);                // swizzled source quarter
      GLOAD_LDS(A + (size_t)(m0 + r) * K + k0 + gq * 8, &As[(w * 32 + half * 16) * 32]);
      GLOAD_LDS(Bt + (size_t)(n0 + r) * K + k0 + gq * 8, &Bs[(w * 32 + half * 16) * 32]);
    }
    __syncthreads();
    bf16x8 af[4], bfr[4];
#pragma unroll
    for (int mi = 0; mi < 4; ++mi) {
      int r = wr + mi * 16 + (l & 15);
      int q = (l >> 4) ^ (r & 3);
      af[mi] = __builtin_bit_cast(bf16x8, *(const us8*)&As[r * 32 + q * 8]);
    }
#pragma unroll
    for (int ni = 0; ni < 4; ++ni) {
      int r = wc + ni * 16 + (l & 15);
      int q = (l >> 4) ^ (r & 3);
      bfr[ni] = __builtin_bit_cast(bf16x8, *(const us8*)&Bs[r * 32 + q * 8]);
    }
#pragma unroll
    for (int mi = 0; mi < 4; ++mi)
#pragma unroll
      for (int ni = 0; ni < 4; ++ni) acc[mi][ni] = MFMA(af[mi], bfr[ni], acc[mi][ni]);
  }
#pragma unroll
  for (int mi = 0; mi < 4; ++mi)
#pragma unroll
    for (int ni = 0; ni < 4; ++ni)
#pragma unroll
      for (int r4 = 0; r4 < 4; ++r4) {
        int row = m0 + wr + mi * 16 + (l >> 4) * 4 + r4;    // b*512 + t
        int rr = ((row & 511) << 5) + (row >> 9);           // t*32 + b
        int col = n0 + wc + ni * 16 + (l & 15);
        C[(size_t)rr * 3072 + col] = f2bf(acc[mi][ni][r4]);
      }
}

// --------------------------- persistent LSTM layer -------------------------
// One direction-phase of one timestep. D is compile-time (0=fwd, 1=bwd).
// Contains: poll(s) -> px promote/issue -> MFMA -> part write -> barrier ->
// epilogue (publish first, then y/finals).
template <int D>
__device__ __forceinline__ void lstm_phase(
    int s, int layer, int m, int w, int l, bool epi,
    int r, int j, int jg, int b,
    const bf16x8 (&wf)[5][4], const float (&bv)[5], float& c,
    unsigned int (&xCur)[6], unsigned int (&xNext)[6],
    const unsigned short* __restrict__ pxd, char* __restrict__ hxg,
    const int (&coff)[4], bool lrow8, bool s1, bool s2,
    int myc, int pbase, int prow,
    float (&part)[4][8][160],
    unsigned short* __restrict__ ybf, float* __restrict__ yf,
    float* __restrict__ finals) {
  int kh = w & 3, nh = w >> 2;
  int t = D ? (511 - s) : s;
  u32x4 ca[4], cb2[4];

  // ---- poll-on-data (skip s=0: h0 == 0) ----
  if (s > 0) {
    const char* cb = hxg + (size_t)(s & 1) * 98304;
    unsigned enc = (unsigned)(s | ((~s & 0xFFFF) << 16));
    bool dn[4];
#pragma unroll
    for (int kk = 0; kk < 4; ++kk) dn[kk] = !lrow8;
    long guard = 0;
    bool ok;
    bool first = true;
    do {
      if (!first) __builtin_amdgcn_s_sleep(1);   // throttle retry traffic
      first = false;
#pragma unroll
      for (int kk = 0; kk < 4; ++kk)
        if (!dn[kk]) chunk2_ld(cb + coff[kk], ca[kk], cb2[kk]);
      asm volatile("s_waitcnt vmcnt(0)" ::: "memory");
      __builtin_amdgcn_sched_barrier(0);
      bool mine = true;
#pragma unroll
      for (int kk = 0; kk < 4; ++kk) {
        dn[kk] = dn[kk] || ((ca[kk][3] == enc) && (cb2[kk][3] == enc));
        mine = mine && dn[kk];
      }
      ok = (__all((int)mine) != 0);
    } while (!ok && ++guard < 300000L);
  }

  // ---- px: promote prefetch, issue next (compiler-managed waits) ----
  if (epi) {
#pragma unroll
    for (int i = 0; i < 6; ++i) xCur[i] = xNext[i];   // loads are 1 iter old
    if (s < 511) {
      int tn = D ? (511 - (s + 1)) : (s + 1);
      const unsigned short* pp = pxd + ((size_t)((tn << 5) + b)) * 3072 + jg;
#pragma unroll
      for (int q6 = 0; q6 < 6; ++q6) xNext[q6] = pp[q6 << 9];
    }
  }

  // ---- MFMA: M=8(pad16) x N=80 x K=128 per wave ----
  f32x4 acc[5];
#pragma unroll
  for (int g5 = 0; g5 < 5; ++g5) acc[g5] = (f32x4){0.f, 0.f, 0.f, 0.f};
  if (s > 0) {
#pragma unroll
    for (int kk = 0; kk < 4; ++kk) {
      u32x4 a = ca[kk], bb = cb2[kk], f;
      f[0] = s1 ? a[1] : (s2 ? a[2] : a[0]);
      f[1] = s1 ? a[2] : (s2 ? bb[0] : a[1]);
      f[2] = s1 ? bb[0] : (s2 ? bb[1] : a[2]);
      f[3] = s1 ? bb[1] : (s2 ? bb[2] : bb[0]);
      bf16x8 av = __builtin_bit_cast(bf16x8, f);
#pragma unroll
      for (int g5 = 0; g5 < 5; ++g5) acc[g5] = MFMA(av, wf[g5][kk], acc[g5]);
    }
  }
  if (l < 32) {
#pragma unroll
    for (int g5 = 0; g5 < 5; ++g5)
#pragma unroll
      for (int r4 = 0; r4 < 4; ++r4)
        part[kh][(l >> 4) * 4 + r4][nh * 80 + g5 * 16 + (l & 15)] = acc[g5][r4];
  }
  __syncthreads();                          // one barrier per phase

  // ---- epilogue + publish (threads 0..255) ----
  if (epi) {
    int cc0 = (j >> 4) * 80 + (j & 15);
    float ps_[5];
#pragma unroll
    for (int g5 = 0; g5 < 5; ++g5) {
      int cc = cc0 + g5 * 16;
      ps_[g5] = part[0][r][cc] + part[1][r][cc] + part[2][r][cc] + part[3][r][cc] + bv[g5];
    }
    float x0 = bf2f(xCur[0]), x1 = bf2f(xCur[1]), x2 = bf2f(xCur[2]);
    float x3 = bf2f(xCur[3]), x4 = bf2f(xCur[4]), x5 = bf2f(xCur[5]);
    float iG = sigf(x0 + ps_[0]);
    float fG = sigf(x1 + ps_[1]);
    float gG = tanh_(x2 + ps_[2]);
    float oG = sigf(x3 + ps_[3]);
    float cn = iG * gG + fG * c;
    c = cn;
    float ht = oG * tanh_(cn);
    float rG = sigf(x4 + ps_[4]);
    ht = rG * ht + (1.f - rG) * x5;

    // publish FIRST (group's next-step critical path)
    if (s < 511) {
      unsigned int hbits = (unsigned int)f2bf(ht);
      unsigned int vv[6];
#pragma unroll
      for (int i = 0; i < 6; ++i)
        vv[i] = __shfl(hbits, (pbase + myc * 6 + i) & 63);
      unsigned int pw0 = vv[0] | (vv[1] << 16);
      unsigned int pw1 = vv[2] | (vv[3] << 16);
      unsigned int pw2 = vv[4] | (vv[5] << 16);
      if (myc == 5) { pw1 = 0; pw2 = 0; }
      if (myc < 6) {
        char* dst = hxg + (size_t)((s + 1) & 1) * 98304 +
                    (size_t)((m * 8 + prow) * 6 + myc) * 16;
        unsigned enc1 = (unsigned)((s + 1) | ((~(s + 1) & 0xFFFF) << 16));
        u32x4 pv = {pw0, pw1, pw2, enc1};
        pub16(dst, pv);
      }
    }

    size_t yo = ((size_t)(b * 512 + t)) * 1024 + D * 512 + jg;
    if (ybf) ybf[yo] = f2bf(ht);
    else     yf[yo] = ht;
    if (s == 511) {
      int fo = (layer * 32 + b) * 1024 + D * 512 + jg;
      finals[fo] = ht;            // final_h
      finals[65536 + fo] = cn;    // final_c
    }
  }
}

// 64 WGs x 512 threads = 4 batch-quarters x 16 members; each WG runs BOTH
// directions, phase-alternated so each dir's exchange RTT hides under the
// other dir's compute. 8 waves: kh = w&3 (K quarter), nh = w>>2 (hidden half).
__global__ __launch_bounds__(512, 1) void k_persist(
    const unsigned short* __restrict__ px,    // [2][512*32][3072] bf16 t-major
    const unsigned short* __restrict__ wp,    // this layer's packed Wh (2 dirs)
    const float* __restrict__ bias_f, const float* __restrict__ bias_b,
    char* __restrict__ hxc,                   // [2 layer][2 buf][8 grp][16 m][8 r][6 c]x16B
    unsigned short* __restrict__ ybf,         // layer0: a1bf, else null
    float* __restrict__ yf,                   // layer1: d_out, else null
    float* __restrict__ finals,               // d_out + 16777216
    int layer) {
  __shared__ float partF[4][8][160];          // 20 KiB
  __shared__ float partB[4][8][160];          // 20 KiB
  int wg = blockIdx.x;
  int q = wg >> 4, m = wg & 15;
  int tid = threadIdx.x;
  int w = tid >> 6, l = tid & 63;
  int kh = w & 3, nh = w >> 2;
  int ns = m * 2 + nh;                        // 16-hidden slice id (0..31)
  const unsigned short* pxdF = px;
  const unsigned short* pxdB = px + (size_t)16384 * 3072;
  char* hxgF = hxc + (size_t)layer * 196608 + (size_t)(q * 2 + 0) * 12288;
  char* hxgB = hxc + (size_t)layer * 196608 + (size_t)(q * 2 + 1) * 12288;

  // ---- Wh fragments register-resident, both dirs: 2 x 80 VGPR ----
  bf16x8 wfF[5][4], wfB[5][4];
#pragma unroll
  for (int g5 = 0; g5 < 5; ++g5)
#pragma unroll
    for (int kk = 0; kk < 4; ++kk) {
      size_t fo = (size_t)((g5 * 32 + ns) * 16 + (kh * 4 + kk)) * 512 + l * 8;
      wfF[g5][kk] = __builtin_bit_cast(bf16x8, *(const us8*)&wp[fo]);
      wfB[g5][kk] = __builtin_bit_cast(bf16x8, *(const us8*)&wp[1310720 + fo]);
    }

  // ---- epilogue constants (threads 0..255 = waves 0..3) ----
  bool epi = tid < 256;
  int r = tid >> 5, j = tid & 31, jg = m * 32 + j, b = q * 8 + r;
  float bvF[5], bvB[5];
#pragma unroll
  for (int g5 = 0; g5 < 5; ++g5) {
    bvF[g5] = bias_f[(g5 << 9) + jg];
    bvB[g5] = bias_b[(g5 << 9) + jg];
  }

  float cF = 0.f, cB = 0.f;
  unsigned int xCurF[6], xNextF[6], xCurB[6], xNextB[6];
  if (epi) {
    const unsigned short* ppF = pxdF + ((size_t)b) * 3072 + jg;              // t=0
    const unsigned short* ppB = pxdB + ((size_t)((511 << 5) + b)) * 3072 + jg;  // t=511
#pragma unroll
    for (int q6 = 0; q6 < 6; ++q6) { xNextF[q6] = ppF[q6 << 9]; xNextB[q6] = ppB[q6 << 9]; }
  }

  // ---- chunk addressing (shared between dirs) ----
  bool lrow8 = (l & 15) < 8;
  int row8 = l & 7;
  int sel = l >> 4;
  int p0 = (sel == 1) ? 1 : (sel == 2) ? 2 : (sel == 3) ? 4 : 0;
  bool s1 = (sel == 1), s2 = (sel == 2);
  int coff[4];
#pragma unroll
  for (int kk = 0; kk < 4; ++kk)
    coff[kk] = (((kh * 4 + kk) * 8 + row8) * 6 + p0) * 16;
  int myc = l & 31, pbase = l & 32, prow = 2 * w + (l >> 5);  // publish (waves 0..3)

  for (int s = 0; s < 512; ++s) {
    lstm_phase<0>(s, layer, m, w, l, epi, r, j, jg, b, wfF, bvF, cF,
                  xCurF, xNextF, pxdF, hxgF, coff, lrow8, s1, s2,
                  myc, pbase, prow, partF, ybf, yf, finals);
    lstm_phase<1>(s, layer, m, w, l, epi, r, j, jg, b, wfB, bvB, cB,
                  xCurB, xNextB, pxdB, hxgB, coff, lrow8, s1, s2,
                  myc, pbase, prow, partB, ybf, yf, finals);
  }
}

// --------------------------- host ------------------------------------------

extern "C" void kernel_launch(void* const* d_in, const int* in_sizes, int n_in,
                              void* d_out, int out_size, void* d_ws, size_t ws_size,
                              hipStream_t stream) {
  (void)in_sizes; (void)n_in; (void)out_size; (void)ws_size;
  const float* x = (const float*)d_in[0];
  const float* Wx[4] = {(const float*)d_in[1], (const float*)d_in[4],
                        (const float*)d_in[7], (const float*)d_in[10]};
  const float* Wh[4] = {(const float*)d_in[2], (const float*)d_in[5],
                        (const float*)d_in[8], (const float*)d_in[11]};
  const float* bs[4] = {(const float*)d_in[3], (const float*)d_in[6],
                        (const float*)d_in[9], (const float*)d_in[12]};

  // ws: px + packed Wh + chunk exchange (~202.4 MiB)
  char* ws = (char*)d_ws;
  unsigned short* px   = (unsigned short*)(ws);
  unsigned short* whp  = (unsigned short*)(ws + 201326592);
  char*           hxc  = (char*)(ws + 211812352);

  // d_out doubles as scratch for transients (all dead before final y writes)
  char* ob = (char*)d_out;
  unsigned short* xbf  = (unsigned short*)(ob);             // 16 MiB, phase A
  unsigned short* wxt0 = (unsigned short*)(ob + 16777216);  // 6 MiB, phase A
  unsigned short* wxt1 = (unsigned short*)(ob + 33554432);  // 12 MiB
  unsigned short* a1bf = (unsigned short*)(ob);             // 32 MiB, phase B
  float* out = (float*)d_out;
  float* finals = out + 16777216;

  k_convert_x<<<8192, 256, 0, stream>>>(x, xbf, 2097152);
  k_pack_wxT<<<dim3(96, 32, 4), 256, 0, stream>>>(Wx[0], Wx[1], Wx[2], Wx[3], wxt0, wxt1);
  k_pack_whp<<<dim3(640, 4), 256, 0, stream>>>(Wh[0], Wh[1], Wh[2], Wh[3], whp);
  hipMemsetAsync(hxc, 0xFF, 393216, stream);   // never decodes as a valid seq

  for (int layer = 0; layer < 2; ++layer) {
    int K = layer ? 1024 : 512;
    const unsigned short* Ag = layer ? a1bf : xbf;
    const unsigned short* wxt = layer ? wxt1 : wxt0;
    k_gemm<<<dim3(128, 24, 2), 256, 0, stream>>>(Ag, wxt, px, K);
    k_persist<<<64, 512, 0, stream>>>(
        px, whp + (size_t)layer * 2621440, bs[layer * 2], bs[layer * 2 + 1],
        hxc, layer ? nullptr : a1bf, layer ? out : nullptr, finals, layer);
  }
}

// Round 12
// 5102.643 us; speedup vs baseline: 1.2128x; 1.2128x over previous
//
#include <hip/hip_runtime.h>

// ---------------------------------------------------------------------------
// StackedBidirectionalLstm  (B=32, T=512, IN=512, H=512, LAYERS=2, bidir, highway)
//
// Round 12: round 11's fwd/bwd phase-alternation (each dir's exchange RTT
// hides under the other dir's compute) with a register budget that FITS:
// 256-thread WGs (4 waves, 1 wave/SIMD -> 512 VGPR budget). Wave w = K-quarter;
// each wave carries BOTH dirs' weights for the member's full 32 hidden:
// wf[5][2][4] x 2 dirs = 320 VGPR. Chunk loads once per step (not twice).
// 64 WGs = 4 batch-quarters x 16 members. Exchange protocol identical to
// passing rounds 6/9/10: 16B chunks {6 bf16 | enc(s)} sc0 sc1, poll-on-data,
// done-mask + s_sleep. partF/partB separate; 1 barrier per phase.
//
//   ws layout (bytes), total ~202.4 MiB:
//     px   @ 0          201,326,592  ([2][512*32][3072] bf16, t-major)
//     whp  @ 201326592   10,485,760  (packed Wh fragments)
//     hxc  @ 211812352      393,216  ([2 layer][2 buf][8 grp][16 m][8 r][6 c]x16B)
//   d_out scratch: phase A xbf/wxt0/wxt1, phase B a1bf (as previous rounds).
// ---------------------------------------------------------------------------

typedef float f32x4 __attribute__((ext_vector_type(4)));
typedef __bf16 bf16x8 __attribute__((ext_vector_type(8)));
typedef unsigned short us8 __attribute__((ext_vector_type(8)));
typedef unsigned short us4 __attribute__((ext_vector_type(4)));
typedef unsigned int u32x4 __attribute__((ext_vector_type(4)));

__device__ __forceinline__ unsigned short f2bf(float f) {
  unsigned int u = __float_as_uint(f);
  u += 0x7FFFu + ((u >> 16) & 1u);            // round-to-nearest-even
  return (unsigned short)(u >> 16);
}
__device__ __forceinline__ float bf2f(unsigned int h) {
  return __uint_as_float(h << 16);
}
__device__ __forceinline__ float sigf(float x) { return 1.0f / (1.0f + __expf(-x)); }
__device__ __forceinline__ float tanh_(float x) { return 2.0f / (1.0f + __expf(-2.0f * x)) - 1.0f; }

#define MFMA(a, b, c) __builtin_amdgcn_mfma_f32_16x16x32_bf16((a), (b), (c), 0, 0, 0)
#define GLOAD_LDS(gp, lp)                                                           \
  __builtin_amdgcn_global_load_lds(                                                 \
      (const __attribute__((address_space(1))) void*)(gp),                          \
      (__attribute__((address_space(3))) void*)(lp), 16, 0, 0)

// Coherent (device/system-scope) 16B pair load; no waitcnt inside.
__device__ __forceinline__ void chunk2_ld(const char* p, u32x4& a, u32x4& b) {
  asm volatile("global_load_dwordx4 %0, %2, off sc0 sc1\n\t"
               "global_load_dwordx4 %1, %2, off offset:16 sc0 sc1"
               : "=&v"(a), "=&v"(b) : "v"(p) : "memory");
}
// Fire-and-forget coherent 16B publish.
__device__ __forceinline__ void pub16(char* p, u32x4 v) {
  asm volatile("global_store_dwordx4 %0, %1, off sc0 sc1" :: "v"(p), "v"(v) : "memory");
}

// --------------------------- prep kernels ----------------------------------

__global__ void k_convert_x(const float* __restrict__ x, unsigned short* __restrict__ xb, int n4) {
  int i = blockIdx.x * blockDim.x + threadIdx.x;
  if (i < n4) {
    float4 v = ((const float4*)x)[i];
    us4 o;
    o[0] = f2bf(v.x); o[1] = f2bf(v.y); o[2] = f2bf(v.z); o[3] = f2bf(v.w);
    ((us4*)xb)[i] = o;
  }
}

// Tiled transpose: WxT[n][k] = bf16(Wx[k][n]); z = layer*2+dir
__global__ __launch_bounds__(256) void k_pack_wxT(
    const float* __restrict__ W0, const float* __restrict__ W1,
    const float* __restrict__ W2, const float* __restrict__ W3,
    unsigned short* __restrict__ o01, unsigned short* __restrict__ o23) {
  int y = blockIdx.z;
  int K = (y >> 1) ? 1024 : 512;
  int kb = blockIdx.y * 32;
  if (kb >= K) return;
  const float* W = (y == 0) ? W0 : (y == 1) ? W1 : (y == 2) ? W2 : W3;
  unsigned short* o = (y >> 1) ? (o23 + (size_t)(y & 1) * 3072 * 1024)
                               : (o01 + (size_t)(y & 1) * 3072 * 512);
  __shared__ float tile[32][33];
  int nb = blockIdx.x * 32;
  int tx = threadIdx.x & 31, ty = threadIdx.x >> 5;   // ty 0..7
#pragma unroll
  for (int r = 0; r < 4; ++r)
    tile[ty + r * 8][tx] = W[(size_t)(kb + ty + r * 8) * 3072 + nb + tx];
  __syncthreads();
#pragma unroll
  for (int r = 0; r < 4; ++r)
    o[(size_t)(nb + ty + r * 8) * K + kb + tx] = f2bf(tile[tx][ty + r * 8]);
}

// Pack Wh (512x2560 f32) into MFMA B-fragments:
// out[(((g*32+ns)*16+ks)*64+lane)*8+e] = Wh[ks*32+(lane>>4)*8+e][g*512+ns*16+(lane&15)]
__global__ void k_pack_whp(const float* __restrict__ W0, const float* __restrict__ W1,
                           const float* __restrict__ W2, const float* __restrict__ W3,
                           unsigned short* __restrict__ out) {
  int y = blockIdx.y;
  const float* W = (y == 0) ? W0 : (y == 1) ? W1 : (y == 2) ? W2 : W3;
  unsigned short* o = out + (size_t)y * 1310720;
  int v = blockIdx.x * 256 + threadIdx.x;   // < 163840
  int lane = v & 63, ks = (v >> 6) & 15, ns = (v >> 10) & 31, g = v >> 15;
  int col = g * 512 + ns * 16 + (lane & 15);
  int kb = ks * 32 + ((lane >> 4) << 3);
  us8 vec;
#pragma unroll
  for (int e = 0; e < 8; ++e) vec[e] = f2bf(W[(size_t)(kb + e) * 2560 + col]);
  *(us8*)&o[(size_t)v * 8] = vec;
}

// --------------------------- bf16 GEMM -------------------------------------
// px[rr][col] with rr = t*32+b (t-major), from A[16384][K] @ Bt[3072][K]^T.
__global__ __launch_bounds__(256) void k_gemm(const unsigned short* __restrict__ A,
                                              const unsigned short* __restrict__ BtBase,
                                              unsigned short* __restrict__ CBase, int K) {
  __shared__ __align__(128) unsigned short As[128 * 32];
  __shared__ __align__(128) unsigned short Bs[128 * 32];
  const unsigned short* Bt = BtBase + (size_t)blockIdx.z * 3072 * K;
  unsigned short* C = CBase + (size_t)blockIdx.z * 16384 * 3072;
  int tid = threadIdx.x;
  int w = tid >> 6, l = tid & 63;
  int m0 = blockIdx.x * 128, n0 = blockIdx.y * 128;
  int wr = (w >> 1) * 64, wc = (w & 1) * 64;
  f32x4 acc[4][4];
#pragma unroll
  for (int i = 0; i < 4; ++i)
#pragma unroll
    for (int j = 0; j < 4; ++j) acc[i][j] = (f32x4){0.f, 0.f, 0.f, 0.f};

  for (int k0 = 0; k0 < K; k0 += 32) {
    __syncthreads();
#pragma unroll
    for (int half = 0; half < 2; ++half) {
      int r = w * 32 + half * 16 + (l >> 2);     // row within tile
      int gq = (l & 3) ^ (r & 3);                // swizzled source quarter
      GLOAD_LDS(A + (size_t)(m0 + r) * K + k0 + gq * 8, &As[(w * 32 + half * 16) * 32]);
      GLOAD_LDS(Bt + (size_t)(n0 + r) * K + k0 + gq * 8, &Bs[(w * 32 + half * 16) * 32]);
    }
    __syncthreads();
    bf16x8 af[4], bfr[4];
#pragma unroll
    for (int mi = 0; mi < 4; ++mi) {
      int r = wr + mi * 16 + (l & 15);
      int q = (l >> 4) ^ (r & 3);
      af[mi] = __builtin_bit_cast(bf16x8, *(const us8*)&As[r * 32 + q * 8]);
    }
#pragma unroll
    for (int ni = 0; ni < 4; ++ni) {
      int r = wc + ni * 16 + (l & 15);
      int q = (l >> 4) ^ (r & 3);
      bfr[ni] = __builtin_bit_cast(bf16x8, *(const us8*)&Bs[r * 32 + q * 8]);
    }
#pragma unroll
    for (int mi = 0; mi < 4; ++mi)
#pragma unroll
      for (int ni = 0; ni < 4; ++ni) acc[mi][ni] = MFMA(af[mi], bfr[ni], acc[mi][ni]);
  }
#pragma unroll
  for (int mi = 0; mi < 4; ++mi)
#pragma unroll
    for (int ni = 0; ni < 4; ++ni)
#pragma unroll
      for (int r4 = 0; r4 < 4; ++r4) {
        int row = m0 + wr + mi * 16 + (l >> 4) * 4 + r4;    // b*512 + t
        int rr = ((row & 511) << 5) + (row >> 9);           // t*32 + b
        int col = n0 + wc + ni * 16 + (l & 15);
        C[(size_t)rr * 3072 + col] = f2bf(acc[mi][ni][r4]);
      }
}

// --------------------------- persistent LSTM layer -------------------------
// One direction-phase of one timestep. D compile-time (0=fwd, 1=bwd).
// poll(s) -> px promote/issue -> MFMA (40) -> part write -> barrier ->
// epilogue (publish first, then y/finals).
template <int D>
__device__ __forceinline__ void lstm_phase(
    int s, int layer, int m, int w, int l,
    int r, int j, int jg, int b,
    const bf16x8 (&wf)[5][2][4], const float (&bv)[5], float& c,
    unsigned int (&xCur)[6], unsigned int (&xNext)[6],
    const unsigned short* __restrict__ pxd, char* __restrict__ hxg,
    const int (&coff)[4], bool lrow8, bool s1, bool s2,
    int myc, int pbase, int prow,
    float (&part)[4][8][160],
    unsigned short* __restrict__ ybf, float* __restrict__ yf,
    float* __restrict__ finals) {
  int t = D ? (511 - s) : s;
  u32x4 ca[4], cb2[4];

  // ---- poll-on-data (skip s=0: h0 == 0) ----
  if (s > 0) {
    const char* cb = hxg + (size_t)(s & 1) * 98304;
    unsigned enc = (unsigned)(s | ((~s & 0xFFFF) << 16));
    bool dn[4];
#pragma unroll
    for (int kk = 0; kk < 4; ++kk) dn[kk] = !lrow8;
    long guard = 0;
    bool ok;
    bool first = true;
    do {
      if (!first) __builtin_amdgcn_s_sleep(1);   // throttle retry traffic
      first = false;
#pragma unroll
      for (int kk = 0; kk < 4; ++kk)
        if (!dn[kk]) chunk2_ld(cb + coff[kk], ca[kk], cb2[kk]);
      asm volatile("s_waitcnt vmcnt(0)" ::: "memory");
      __builtin_amdgcn_sched_barrier(0);
      bool mine = true;
#pragma unroll
      for (int kk = 0; kk < 4; ++kk) {
        dn[kk] = dn[kk] || ((ca[kk][3] == enc) && (cb2[kk][3] == enc));
        mine = mine && dn[kk];
      }
      ok = (__all((int)mine) != 0);
    } while (!ok && ++guard < 300000L);
  }

  // ---- px: promote prefetch, issue next (compiler-managed waits) ----
#pragma unroll
  for (int i = 0; i < 6; ++i) xCur[i] = xNext[i];   // loads are 1 iter old
  if (s < 511) {
    int tn = D ? (511 - (s + 1)) : (s + 1);
    const unsigned short* pp = pxd + ((size_t)((tn << 5) + b)) * 3072 + jg;
#pragma unroll
    for (int q6 = 0; q6 < 6; ++q6) xNext[q6] = pp[q6 << 9];
  }

  // ---- MFMA: M=8(pad16) x N=160 x K=128 per wave ----
  f32x4 acc[5][2];
#pragma unroll
  for (int g5 = 0; g5 < 5; ++g5)
#pragma unroll
    for (int nh = 0; nh < 2; ++nh) acc[g5][nh] = (f32x4){0.f, 0.f, 0.f, 0.f};
  if (s > 0) {
#pragma unroll
    for (int kk = 0; kk < 4; ++kk) {
      u32x4 a = ca[kk], bb = cb2[kk], f;
      f[0] = s1 ? a[1] : (s2 ? a[2] : a[0]);
      f[1] = s1 ? a[2] : (s2 ? bb[0] : a[1]);
      f[2] = s1 ? bb[0] : (s2 ? bb[1] : a[2]);
      f[3] = s1 ? bb[1] : (s2 ? bb[2] : bb[0]);
      bf16x8 av = __builtin_bit_cast(bf16x8, f);
#pragma unroll
      for (int g5 = 0; g5 < 5; ++g5)
#pragma unroll
        for (int nh = 0; nh < 2; ++nh)
          acc[g5][nh] = MFMA(av, wf[g5][nh][kk], acc[g5][nh]);
    }
  }
  if (l < 32) {
#pragma unroll
    for (int g5 = 0; g5 < 5; ++g5)
#pragma unroll
      for (int nh = 0; nh < 2; ++nh)
#pragma unroll
        for (int r4 = 0; r4 < 4; ++r4)
          part[w][(l >> 4) * 4 + r4][nh * 80 + g5 * 16 + (l & 15)] = acc[g5][nh][r4];
  }
  __syncthreads();                          // one barrier per phase

  // ---- epilogue + publish (all 256 threads: 1 output each) ----
  {
    int cc0 = (j >> 4) * 80 + (j & 15);
    float ps_[5];
#pragma unroll
    for (int g5 = 0; g5 < 5; ++g5) {
      int cc = cc0 + g5 * 16;
      ps_[g5] = part[0][r][cc] + part[1][r][cc] + part[2][r][cc] + part[3][r][cc] + bv[g5];
    }
    float x0 = bf2f(xCur[0]), x1 = bf2f(xCur[1]), x2 = bf2f(xCur[2]);
    float x3 = bf2f(xCur[3]), x4 = bf2f(xCur[4]), x5 = bf2f(xCur[5]);
    float iG = sigf(x0 + ps_[0]);
    float fG = sigf(x1 + ps_[1]);
    float gG = tanh_(x2 + ps_[2]);
    float oG = sigf(x3 + ps_[3]);
    float cn = iG * gG + fG * c;
    c = cn;
    float ht = oG * tanh_(cn);
    float rG = sigf(x4 + ps_[4]);
    ht = rG * ht + (1.f - rG) * x5;

    // publish FIRST (group's next-step critical path)
    if (s < 511) {
      unsigned int hbits = (unsigned int)f2bf(ht);
      unsigned int vv[6];
#pragma unroll
      for (int i = 0; i < 6; ++i)
        vv[i] = __shfl(hbits, (pbase + myc * 6 + i) & 63);
      unsigned int pw0 = vv[0] | (vv[1] << 16);
      unsigned int pw1 = vv[2] | (vv[3] << 16);
      unsigned int pw2 = vv[4] | (vv[5] << 16);
      if (myc == 5) { pw1 = 0; pw2 = 0; }
      if (myc < 6) {
        char* dst = hxg + (size_t)((s + 1) & 1) * 98304 +
                    (size_t)((m * 8 + prow) * 6 + myc) * 16;
        unsigned enc1 = (unsigned)((s + 1) | ((~(s + 1) & 0xFFFF) << 16));
        u32x4 pv = {pw0, pw1, pw2, enc1};
        pub16(dst, pv);
      }
    }

    size_t yo = ((size_t)(b * 512 + t)) * 1024 + D * 512 + jg;
    if (ybf) ybf[yo] = f2bf(ht);
    else     yf[yo] = ht;
    if (s == 511) {
      int fo = (layer * 32 + b) * 1024 + D * 512 + jg;
      finals[fo] = ht;            // final_h
      finals[65536 + fo] = cn;    // final_c
    }
  }
}

// 64 WGs x 256 threads = 4 batch-quarters x 16 members; each WG runs BOTH
// directions phase-alternated. 4 waves: w = K-quarter; each wave carries both
// dirs' weights for the member's full 32 hidden (wf[5][2][4] x2 = 320 VGPR).
__global__ __launch_bounds__(256, 1) void k_persist(
    const unsigned short* __restrict__ px,    // [2][512*32][3072] bf16 t-major
    const unsigned short* __restrict__ wp,    // this layer's packed Wh (2 dirs)
    const float* __restrict__ bias_f, const float* __restrict__ bias_b,
    char* __restrict__ hxc,                   // [2 layer][2 buf][8 grp][16 m][8 r][6 c]x16B
    unsigned short* __restrict__ ybf,         // layer0: a1bf, else null
    float* __restrict__ yf,                   // layer1: d_out, else null
    float* __restrict__ finals,               // d_out + 16777216
    int layer) {
  __shared__ float partF[4][8][160];          // 20 KiB
  __shared__ float partB[4][8][160];          // 20 KiB
  int wg = blockIdx.x;
  int q = wg >> 4, m = wg & 15;
  int tid = threadIdx.x;
  int w = tid >> 6, l = tid & 63;             // w = K-quarter (0..3)
  const unsigned short* pxdF = px;
  const unsigned short* pxdB = px + (size_t)16384 * 3072;
  char* hxgF = hxc + (size_t)layer * 196608 + (size_t)(q * 2 + 0) * 12288;
  char* hxgB = hxc + (size_t)layer * 196608 + (size_t)(q * 2 + 1) * 12288;

  // ---- Wh fragments register-resident, both dirs, both hidden halves ----
  bf16x8 wfF[5][2][4], wfB[5][2][4];
#pragma unroll
  for (int g5 = 0; g5 < 5; ++g5)
#pragma unroll
    for (int nh = 0; nh < 2; ++nh)
#pragma unroll
      for (int kk = 0; kk < 4; ++kk) {
        size_t fo = (size_t)((g5 * 32 + (m * 2 + nh)) * 16 + (w * 4 + kk)) * 512 + l * 8;
        wfF[g5][nh][kk] = __builtin_bit_cast(bf16x8, *(const us8*)&wp[fo]);
        wfB[g5][nh][kk] = __builtin_bit_cast(bf16x8, *(const us8*)&wp[1310720 + fo]);
      }

  // ---- epilogue constants: 1 output (row r, hidden jg) per thread ----
  int r = tid >> 5, j = tid & 31, jg = m * 32 + j, b = q * 8 + r;
  float bvF[5], bvB[5];
#pragma unroll
  for (int g5 = 0; g5 < 5; ++g5) {
    bvF[g5] = bias_f[(g5 << 9) + jg];
    bvB[g5] = bias_b[(g5 << 9) + jg];
  }

  float cF = 0.f, cB = 0.f;
  unsigned int xCurF[6], xNextF[6], xCurB[6], xNextB[6];
  {
    const unsigned short* ppF = pxdF + ((size_t)b) * 3072 + jg;                 // t=0
    const unsigned short* ppB = pxdB + ((size_t)((511 << 5) + b)) * 3072 + jg;  // t=511
#pragma unroll
    for (int q6 = 0; q6 < 6; ++q6) { xNextF[q6] = ppF[q6 << 9]; xNextB[q6] = ppB[q6 << 9]; }
  }

  // ---- chunk addressing (shared between dirs) ----
  bool lrow8 = (l & 15) < 8;
  int row8 = l & 7;
  int sel = l >> 4;
  int p0 = (sel == 1) ? 1 : (sel == 2) ? 2 : (sel == 3) ? 4 : 0;
  bool s1 = (sel == 1), s2 = (sel == 2);
  int coff[4];
#pragma unroll
  for (int kk = 0; kk < 4; ++kk)
    coff[kk] = (((w * 4 + kk) * 8 + row8) * 6 + p0) * 16;
  int myc = l & 31, pbase = l & 32, prow = 2 * w + (l >> 5);  // publish rows 0..7

  for (int s = 0; s < 512; ++s) {
    lstm_phase<0>(s, layer, m, w, l, r, j, jg, b, wfF, bvF, cF,
                  xCurF, xNextF, pxdF, hxgF, coff, lrow8, s1, s2,
                  myc, pbase, prow, partF, ybf, yf, finals);
    lstm_phase<1>(s, layer, m, w, l, r, j, jg, b, wfB, bvB, cB,
                  xCurB, xNextB, pxdB, hxgB, coff, lrow8, s1, s2,
                  myc, pbase, prow, partB, ybf, yf, finals);
  }
}

// --------------------------- host ------------------------------------------

extern "C" void kernel_launch(void* const* d_in, const int* in_sizes, int n_in,
                              void* d_out, int out_size, void* d_ws, size_t ws_size,
                              hipStream_t stream) {
  (void)in_sizes; (void)n_in; (void)out_size; (void)ws_size;
  const float* x = (const float*)d_in[0];
  const float* Wx[4] = {(const float*)d_in[1], (const float*)d_in[4],
                        (const float*)d_in[7], (const float*)d_in[10]};
  const float* Wh[4] = {(const float*)d_in[2], (const float*)d_in[5],
                        (const float*)d_in[8], (const float*)d_in[11]};
  const float* bs[4] = {(const float*)d_in[3], (const float*)d_in[6],
                        (const float*)d_in[9], (const float*)d_in[12]};

  // ws: px + packed Wh + chunk exchange (~202.4 MiB)
  char* ws = (char*)d_ws;
  unsigned short* px   = (unsigned short*)(ws);
  unsigned short* whp  = (unsigned short*)(ws + 201326592);
  char*           hxc  = (char*)(ws + 211812352);

  // d_out doubles as scratch for transients (all dead before final y writes)
  char* ob = (char*)d_out;
  unsigned short* xbf  = (unsigned short*)(ob);             // 16 MiB, phase A
  unsigned short* wxt0 = (unsigned short*)(ob + 16777216);  // 6 MiB, phase A
  unsigned short* wxt1 = (unsigned short*)(ob + 33554432);  // 12 MiB
  unsigned short* a1bf = (unsigned short*)(ob);             // 32 MiB, phase B
  float* out = (float*)d_out;
  float* finals = out + 16777216;

  k_convert_x<<<8192, 256, 0, stream>>>(x, xbf, 2097152);
  k_pack_wxT<<<dim3(96, 32, 4), 256, 0, stream>>>(Wx[0], Wx[1], Wx[2], Wx[3], wxt0, wxt1);
  k_pack_whp<<<dim3(640, 4), 256, 0, stream>>>(Wh[0], Wh[1], Wh[2], Wh[3], whp);
  hipMemsetAsync(hxc, 0xFF, 393216, stream);   // never decodes as a valid seq

  for (int layer = 0; layer < 2; ++layer) {
    int K = layer ? 1024 : 512;
    const unsigned short* Ag = layer ? a1bf : xbf;
    const unsigned short* wxt = layer ? wxt1 : wxt0;
    k_gemm<<<dim3(128, 24, 2), 256, 0, stream>>>(Ag, wxt, px, K);
    k_persist<<<64, 256, 0, stream>>>(
        px, whp + (size_t)layer * 2621440, bs[layer * 2], bs[layer * 2 + 1],
        hxc, layer ? nullptr : a1bf, layer ? out : nullptr, finals, layer);
  }
}

// Round 13
// 2703.561 us; speedup vs baseline: 2.2890x; 1.8874x over previous
//
#include <hip/hip_runtime.h>

// ---------------------------------------------------------------------------
// StackedBidirectionalLstm  (B=32, T=512, IN=512, H=512, LAYERS=2, bidir, highway)
//
// Round 13 = round 10 (best passing: 128 WGs = 8 groups x 16 members, MALL
// chunk exchange {6 bf16 | enc(s)} sc0 sc1, weights register-resident,
// px register double-buffer) with the poll path rebuilt:
//   - partition-poll: 768 chunks/group assigned 1-2 per thread (NO redundant
//     reads; per-WG sample 32KB -> 12KB, grid poll pressure ~10x lower)
//   - each thread spins only on its own chunks, deposits payloads into a
//     padded LDS image hl[8][520]; __syncthreads is the AND-reduction
//   - MFMA A-fragments read from LDS (b128, 16B-aligned, low-conflict);
//     the chunk->fragment register shuffle (sel/cndmask) is deleted
//
//   ws layout (bytes), total ~202.4 MiB:
//     px   @ 0          201,326,592  ([2][512*32][3072] bf16, t-major)
//     whp  @ 201326592   10,485,760  (packed Wh fragments)
//     hxc  @ 211812352      393,216  ([2 layer][2 buf][8 grp][16 m][8 r][6 c]x16B)
//   d_out scratch: phase A xbf/wxt0/wxt1, phase B a1bf (as previous rounds).
// ---------------------------------------------------------------------------

typedef float f32x4 __attribute__((ext_vector_type(4)));
typedef __bf16 bf16x8 __attribute__((ext_vector_type(8)));
typedef unsigned short us8 __attribute__((ext_vector_type(8)));
typedef unsigned short us4 __attribute__((ext_vector_type(4)));
typedef unsigned int u32x4 __attribute__((ext_vector_type(4)));

__device__ __forceinline__ unsigned short f2bf(float f) {
  unsigned int u = __float_as_uint(f);
  u += 0x7FFFu + ((u >> 16) & 1u);            // round-to-nearest-even
  return (unsigned short)(u >> 16);
}
__device__ __forceinline__ float bf2f(unsigned int h) {
  return __uint_as_float(h << 16);
}
__device__ __forceinline__ float sigf(float x) { return 1.0f / (1.0f + __expf(-x)); }
__device__ __forceinline__ float tanh_(float x) { return 2.0f / (1.0f + __expf(-2.0f * x)) - 1.0f; }

#define MFMA(a, b, c) __builtin_amdgcn_mfma_f32_16x16x32_bf16((a), (b), (c), 0, 0, 0)
#define GLOAD_LDS(gp, lp)                                                           \
  __builtin_amdgcn_global_load_lds(                                                 \
      (const __attribute__((address_space(1))) void*)(gp),                          \
      (__attribute__((address_space(3))) void*)(lp), 16, 0, 0)

// Coherent (MALL) 16B chunk load; no waitcnt inside.
__device__ __forceinline__ void chunk1_ld(const char* p, u32x4& v) {
  asm volatile("global_load_dwordx4 %0, %1, off sc0 sc1"
               : "=&v"(v) : "v"(p) : "memory");
}
// Fire-and-forget coherent 16B publish.
__device__ __forceinline__ void pub16(char* p, u32x4 v) {
  asm volatile("global_store_dwordx4 %0, %1, off sc0 sc1" :: "v"(p), "v"(v) : "memory");
}

// --------------------------- prep kernels ----------------------------------

__global__ void k_convert_x(const float* __restrict__ x, unsigned short* __restrict__ xb, int n4) {
  int i = blockIdx.x * blockDim.x + threadIdx.x;
  if (i < n4) {
    float4 v = ((const float4*)x)[i];
    us4 o;
    o[0] = f2bf(v.x); o[1] = f2bf(v.y); o[2] = f2bf(v.z); o[3] = f2bf(v.w);
    ((us4*)xb)[i] = o;
  }
}

// Tiled transpose: WxT[n][k] = bf16(Wx[k][n]); z = layer*2+dir
__global__ __launch_bounds__(256) void k_pack_wxT(
    const float* __restrict__ W0, const float* __restrict__ W1,
    const float* __restrict__ W2, const float* __restrict__ W3,
    unsigned short* __restrict__ o01, unsigned short* __restrict__ o23) {
  int y = blockIdx.z;
  int K = (y >> 1) ? 1024 : 512;
  int kb = blockIdx.y * 32;
  if (kb >= K) return;
  const float* W = (y == 0) ? W0 : (y == 1) ? W1 : (y == 2) ? W2 : W3;
  unsigned short* o = (y >> 1) ? (o23 + (size_t)(y & 1) * 3072 * 1024)
                               : (o01 + (size_t)(y & 1) * 3072 * 512);
  __shared__ float tile[32][33];
  int nb = blockIdx.x * 32;
  int tx = threadIdx.x & 31, ty = threadIdx.x >> 5;   // ty 0..7
#pragma unroll
  for (int r = 0; r < 4; ++r)
    tile[ty + r * 8][tx] = W[(size_t)(kb + ty + r * 8) * 3072 + nb + tx];
  __syncthreads();
#pragma unroll
  for (int r = 0; r < 4; ++r)
    o[(size_t)(nb + ty + r * 8) * K + kb + tx] = f2bf(tile[tx][ty + r * 8]);
}

// Pack Wh (512x2560 f32) into MFMA B-fragments:
// out[(((g*32+ns)*16+ks)*64+lane)*8+e] = Wh[ks*32+(lane>>4)*8+e][g*512+ns*16+(lane&15)]
__global__ void k_pack_whp(const float* __restrict__ W0, const float* __restrict__ W1,
                           const float* __restrict__ W2, const float* __restrict__ W3,
                           unsigned short* __restrict__ out) {
  int y = blockIdx.y;
  const float* W = (y == 0) ? W0 : (y == 1) ? W1 : (y == 2) ? W2 : W3;
  unsigned short* o = out + (size_t)y * 1310720;
  int v = blockIdx.x * 256 + threadIdx.x;   // < 163840
  int lane = v & 63, ks = (v >> 6) & 15, ns = (v >> 10) & 31, g = v >> 15;
  int col = g * 512 + ns * 16 + (lane & 15);
  int kb = ks * 32 + ((lane >> 4) << 3);
  us8 vec;
#pragma unroll
  for (int e = 0; e < 8; ++e) vec[e] = f2bf(W[(size_t)(kb + e) * 2560 + col]);
  *(us8*)&o[(size_t)v * 8] = vec;
}

// --------------------------- bf16 GEMM -------------------------------------
// px[rr][col] with rr = t*32+b (t-major), from A[16384][K] @ Bt[3072][K]^T.
__global__ __launch_bounds__(256) void k_gemm(const unsigned short* __restrict__ A,
                                              const unsigned short* __restrict__ BtBase,
                                              unsigned short* __restrict__ CBase, int K) {
  __shared__ __align__(128) unsigned short As[128 * 32];
  __shared__ __align__(128) unsigned short Bs[128 * 32];
  const unsigned short* Bt = BtBase + (size_t)blockIdx.z * 3072 * K;
  unsigned short* C = CBase + (size_t)blockIdx.z * 16384 * 3072;
  int tid = threadIdx.x;
  int w = tid >> 6, l = tid & 63;
  int m0 = blockIdx.x * 128, n0 = blockIdx.y * 128;
  int wr = (w >> 1) * 64, wc = (w & 1) * 64;
  f32x4 acc[4][4];
#pragma unroll
  for (int i = 0; i < 4; ++i)
#pragma unroll
    for (int j = 0; j < 4; ++j) acc[i][j] = (f32x4){0.f, 0.f, 0.f, 0.f};

  for (int k0 = 0; k0 < K; k0 += 32) {
    __syncthreads();
#pragma unroll
    for (int half = 0; half < 2; ++half) {
      int r = w * 32 + half * 16 + (l >> 2);     // row within tile
      int gq = (l & 3) ^ (r & 3);                // swizzled source quarter
      GLOAD_LDS(A + (size_t)(m0 + r) * K + k0 + gq * 8, &As[(w * 32 + half * 16) * 32]);
      GLOAD_LDS(Bt + (size_t)(n0 + r) * K + k0 + gq * 8, &Bs[(w * 32 + half * 16) * 32]);
    }
    __syncthreads();
    bf16x8 af[4], bfr[4];
#pragma unroll
    for (int mi = 0; mi < 4; ++mi) {
      int r = wr + mi * 16 + (l & 15);
      int q = (l >> 4) ^ (r & 3);
      af[mi] = __builtin_bit_cast(bf16x8, *(const us8*)&As[r * 32 + q * 8]);
    }
#pragma unroll
    for (int ni = 0; ni < 4; ++ni) {
      int r = wc + ni * 16 + (l & 15);
      int q = (l >> 4) ^ (r & 3);
      bfr[ni] = __builtin_bit_cast(bf16x8, *(const us8*)&Bs[r * 32 + q * 8]);
    }
#pragma unroll
    for (int mi = 0; mi < 4; ++mi)
#pragma unroll
      for (int ni = 0; ni < 4; ++ni) acc[mi][ni] = MFMA(af[mi], bfr[ni], acc[mi][ni]);
  }
#pragma unroll
  for (int mi = 0; mi < 4; ++mi)
#pragma unroll
    for (int ni = 0; ni < 4; ++ni)
#pragma unroll
      for (int r4 = 0; r4 < 4; ++r4) {
        int row = m0 + wr + mi * 16 + (l >> 4) * 4 + r4;    // b*512 + t
        int rr = ((row & 511) << 5) + (row >> 9);           // t*32 + b
        int col = n0 + wc + ni * 16 + (l & 15);
        C[(size_t)rr * 3072 + col] = f2bf(acc[mi][ni][r4]);
      }
}

// --------------------------- persistent LSTM layer -------------------------
// 128 WGs x 512 threads = 8 groups (dir d, batch-quarter q) x 16 members.
// Member m owns hidden units m*32..m*32+31. 8 waves: kh = w&3 (K quarter),
// nh = w>>2 (hidden half); wf[5][4] = 80 VGPR/wave, register-resident.
// Exchange: 768 chunks/group {6 bf16 | enc(s)}; each thread spins on 1-2
// DISTINCT chunks, deposits payloads to LDS hl[8][520]; barrier = AND-reduce;
// MFMA A-fragments read from LDS.
__global__ __launch_bounds__(512, 1) void k_persist(
    const unsigned short* __restrict__ px,    // [2][512*32][3072] bf16 t-major
    const unsigned short* __restrict__ wp,    // this layer's packed Wh (2 dirs)
    const float* __restrict__ bias_f, const float* __restrict__ bias_b,
    char* __restrict__ hxc,                   // [2 layer][2 buf][8 grp][16 m][8 r][6 c]x16B
    unsigned short* __restrict__ ybf,         // layer0: a1bf, else null
    float* __restrict__ yf,                   // layer1: d_out, else null
    float* __restrict__ finals,               // d_out + 16777216
    int layer) {
  __shared__ float part[2][4][8][160];        // 40 KiB, parity-buffered
  __shared__ unsigned short hl[8 * 520];      // 8.125 KiB padded h image
  int wg = blockIdx.x;
  int grp = wg >> 4, m = wg & 15;
  int d = grp & 1, q = grp >> 1;
  int tid = threadIdx.x;
  int w = tid >> 6, l = tid & 63;
  int kh = w & 3, nh = w >> 2;
  int ns = m * 2 + nh;                        // 16-hidden slice id (0..31)
  const unsigned short* wpd = wp + (size_t)d * 1310720;
  const unsigned short* pxd = px + (size_t)d * 16384 * 3072;
  const float* bias = d ? bias_b : bias_f;
  char* hxg = hxc + (size_t)layer * 196608 + (size_t)grp * 12288;

  // ---- Wh fragments register-resident: wf[gate][kk], this wave's K-quarter
  bf16x8 wf[5][4];
#pragma unroll
  for (int g5 = 0; g5 < 5; ++g5)
#pragma unroll
    for (int kk = 0; kk < 4; ++kk)
      wf[g5][kk] = __builtin_bit_cast(
          bf16x8,
          *(const us8*)&wpd[(size_t)((g5 * 32 + ns) * 16 + (kh * 4 + kk)) * 512 + l * 8]);

  // ---- epilogue constants (threads 0..255 = waves 0..3) ----
  bool epi = tid < 256;
  int r = tid >> 5, j = tid & 31, jg = m * 32 + j, b = q * 8 + r;
  float bv[5];
#pragma unroll
  for (int g5 = 0; g5 < 5; ++g5) bv[g5] = bias[(g5 << 9) + jg];

  float c = 0.f;
  unsigned int xCur[6], xNext[6];             // px register double-buffer
  if (epi) {
    int t0 = d ? 511 : 0;
    const unsigned short* pp = pxd + ((size_t)((t0 << 5) + b)) * 3072 + jg;
#pragma unroll
    for (int q6 = 0; q6 < 6; ++q6) xNext[q6] = pp[q6 << 9];
  }

  // ---- partition-poll assignment: chunks c0 = tid, c1 = 512+tid (tid<256)
  int c0 = tid;
  int c1 = 512 + tid;
  bool has1 = tid < 256;
  int m8r0 = c0 / 6, myc0 = c0 - m8r0 * 6;
  int off0 = (m8r0 & 7) * 520 + (m8r0 >> 3) * 32 + myc0 * 6;   // elems
  bool is5_0 = (myc0 == 5);
  int m8r1 = c1 / 6, myc1 = c1 - m8r1 * 6;
  int off1 = (m8r1 & 7) * 520 + (m8r1 >> 3) * 32 + myc1 * 6;
  bool is5_1 = (myc1 == 5);

  // ---- A-fragment LDS base (16B-aligned): row (l&7), quarter kh ----
  int fbase = (l & 7) * 520 + kh * 128 + ((l >> 4) << 3);

  int myc = l & 31, pbase = l & 32, prow = 2 * w + (l >> 5);  // publish (waves 0..3)

  for (int s = 0; s < 512; ++s) {
    int t = d ? (511 - s) : s;

    // ---- partition-poll + LDS deposit (skip s=0: h0 == 0) ----
    if (s > 0) {
      const char* cb = hxg + (size_t)(s & 1) * 98304;
      const char* a0 = cb + (size_t)c0 * 16;
      const char* a1 = cb + (size_t)c1 * 16;
      unsigned enc = (unsigned)(s | ((~s & 0xFFFF) << 16));
      u32x4 v0, v1;
      bool d0 = false, d1 = !has1;
      long guard = 0;
      bool first = true, ok;
      do {
        if (!first) __builtin_amdgcn_s_sleep(1);   // throttle retry traffic
        first = false;
        if (!d0) chunk1_ld(a0, v0);
        if (!d1) chunk1_ld(a1, v1);
        asm volatile("s_waitcnt vmcnt(0)" ::: "memory");
        __builtin_amdgcn_sched_barrier(0);
        d0 = d0 || (v0[3] == enc);
        d1 = d1 || (v1[3] == enc);
        ok = (__all((int)(d0 && d1)) != 0);
      } while (!ok && ++guard < 300000L);
      // deposit payloads (dword-aligned LDS writes)
      {
        unsigned int* pw = (unsigned int*)((char*)hl + off0 * 2);
        pw[0] = v0[0];
        if (!is5_0) { pw[1] = v0[1]; pw[2] = v0[2]; }
        if (has1) {
          unsigned int* pw1 = (unsigned int*)((char*)hl + off1 * 2);
          pw1[0] = v1[0];
          if (!is5_1) { pw1[1] = v1[1]; pw1[2] = v1[2]; }
        }
      }
    }

    // ---- px: promote prefetch, issue next (compiler-managed waits) ----
    if (epi) {
#pragma unroll
      for (int i = 0; i < 6; ++i) xCur[i] = xNext[i];   // loads are 1 iter old
      if (s < 511) {
        int tn = d ? (511 - (s + 1)) : (s + 1);
        const unsigned short* pp = pxd + ((size_t)((tn << 5) + b)) * 3072 + jg;
#pragma unroll
        for (int q6 = 0; q6 < 6; ++q6) xNext[q6] = pp[q6 << 9];
      }
    }

    __syncthreads();                          // B1: hl image complete

    // ---- MFMA: M=8(pad16) x N=80 x K=128 per wave, A-frags from LDS ----
    f32x4 acc[5];
#pragma unroll
    for (int g5 = 0; g5 < 5; ++g5) acc[g5] = (f32x4){0.f, 0.f, 0.f, 0.f};
    if (s > 0) {
#pragma unroll
      for (int kk = 0; kk < 4; ++kk) {
        bf16x8 av = __builtin_bit_cast(bf16x8, *(const us8*)&hl[fbase + kk * 32]);
#pragma unroll
        for (int g5 = 0; g5 < 5; ++g5) acc[g5] = MFMA(av, wf[g5][kk], acc[g5]);
      }
    }
    if (l < 32) {
#pragma unroll
      for (int g5 = 0; g5 < 5; ++g5)
#pragma unroll
        for (int r4 = 0; r4 < 4; ++r4)
          part[s & 1][kh][(l >> 4) * 4 + r4][nh * 80 + g5 * 16 + (l & 15)] = acc[g5][r4];
    }
    __syncthreads();                          // B2: part ready

    // ---- epilogue + publish (threads 0..255) ----
    if (epi) {
      int cc0 = (j >> 4) * 80 + (j & 15);
      float ps_[5];
#pragma unroll
      for (int g5 = 0; g5 < 5; ++g5) {
        int cc = cc0 + g5 * 16;
        ps_[g5] = part[s & 1][0][r][cc] + part[s & 1][1][r][cc] +
                  part[s & 1][2][r][cc] + part[s & 1][3][r][cc] + bv[g5];
      }
      float x0 = bf2f(xCur[0]), x1 = bf2f(xCur[1]), x2 = bf2f(xCur[2]);
      float x3 = bf2f(xCur[3]), x4 = bf2f(xCur[4]), x5 = bf2f(xCur[5]);
      float iG = sigf(x0 + ps_[0]);
      float fG = sigf(x1 + ps_[1]);
      float gG = tanh_(x2 + ps_[2]);
      float oG = sigf(x3 + ps_[3]);
      float cn = iG * gG + fG * c;
      c = cn;
      float ht = oG * tanh_(cn);
      float rG = sigf(x4 + ps_[4]);
      ht = rG * ht + (1.f - rG) * x5;

      // publish FIRST (group's next-step critical path)
      if (s < 511) {
        unsigned int hbits = (unsigned int)f2bf(ht);
        unsigned int vv[6];
#pragma unroll
        for (int i = 0; i < 6; ++i)
          vv[i] = __shfl(hbits, (pbase + myc * 6 + i) & 63);
        unsigned int pw0 = vv[0] | (vv[1] << 16);
        unsigned int pw1 = vv[2] | (vv[3] << 16);
        unsigned int pw2 = vv[4] | (vv[5] << 16);
        if (myc == 5) { pw1 = 0; pw2 = 0; }
        if (myc < 6) {
          char* dst = hxg + (size_t)((s + 1) & 1) * 98304 +
                      (size_t)((m * 8 + prow) * 6 + myc) * 16;
          unsigned enc1 = (unsigned)((s + 1) | ((~(s + 1) & 0xFFFF) << 16));
          u32x4 pv = {pw0, pw1, pw2, enc1};
          pub16(dst, pv);
        }
      }

      size_t yo = ((size_t)(b * 512 + t)) * 1024 + d * 512 + jg;
      if (ybf) ybf[yo] = f2bf(ht);
      else     yf[yo] = ht;
      if (s == 511) {
        int fo = (layer * 32 + b) * 1024 + d * 512 + jg;
        finals[fo] = ht;            // final_h
        finals[65536 + fo] = cn;    // final_c
      }
    }
  }
}

// --------------------------- host ------------------------------------------

extern "C" void kernel_launch(void* const* d_in, const int* in_sizes, int n_in,
                              void* d_out, int out_size, void* d_ws, size_t ws_size,
                              hipStream_t stream) {
  (void)in_sizes; (void)n_in; (void)out_size; (void)ws_size;
  const float* x = (const float*)d_in[0];
  const float* Wx[4] = {(const float*)d_in[1], (const float*)d_in[4],
                        (const float*)d_in[7], (const float*)d_in[10]};
  const float* Wh[4] = {(const float*)d_in[2], (const float*)d_in[5],
                        (const float*)d_in[8], (const float*)d_in[11]};
  const float* bs[4] = {(const float*)d_in[3], (const float*)d_in[6],
                        (const float*)d_in[9], (const float*)d_in[12]};

  // ws: px + packed Wh + chunk exchange (~202.4 MiB)
  char* ws = (char*)d_ws;
  unsigned short* px   = (unsigned short*)(ws);
  unsigned short* whp  = (unsigned short*)(ws + 201326592);
  char*           hxc  = (char*)(ws + 211812352);

  // d_out doubles as scratch for transients (all dead before final y writes)
  char* ob = (char*)d_out;
  unsigned short* xbf  = (unsigned short*)(ob);             // 16 MiB, phase A
  unsigned short* wxt0 = (unsigned short*)(ob + 16777216);  // 6 MiB, phase A
  unsigned short* wxt1 = (unsigned short*)(ob + 33554432);  // 12 MiB
  unsigned short* a1bf = (unsigned short*)(ob);             // 32 MiB, phase B
  float* out = (float*)d_out;
  float* finals = out + 16777216;

  k_convert_x<<<8192, 256, 0, stream>>>(x, xbf, 2097152);
  k_pack_wxT<<<dim3(96, 32, 4), 256, 0, stream>>>(Wx[0], Wx[1], Wx[2], Wx[3], wxt0, wxt1);
  k_pack_whp<<<dim3(640, 4), 256, 0, stream>>>(Wh[0], Wh[1], Wh[2], Wh[3], whp);
  hipMemsetAsync(hxc, 0xFF, 393216, stream);   // never decodes as a valid seq

  for (int layer = 0; layer < 2; ++layer) {
    int K = layer ? 1024 : 512;
    const unsigned short* Ag = layer ? a1bf : xbf;
    const unsigned short* wxt = layer ? wxt1 : wxt0;
    k_gemm<<<dim3(128, 24, 2), 256, 0, stream>>>(Ag, wxt, px, K);
    k_persist<<<128, 512, 0, stream>>>(
        px, whp + (size_t)layer * 2621440, bs[layer * 2], bs[layer * 2 + 1],
        hxc, layer ? nullptr : a1bf, layer ? out : nullptr, finals, layer);
  }
}

// Round 14
// 2636.849 us; speedup vs baseline: 2.3469x; 1.0253x over previous
//
#include <hip/hip_runtime.h>

// ---------------------------------------------------------------------------
// StackedBidirectionalLstm  (B=32, T=512, IN=512, H=512, LAYERS=2, bidir, highway)
//
// Round 14 = round 13 (PASSING: partition-poll + LDS h-image + register-
// resident weights) + two targeted fixes:
//   (a) own-member short-circuit: epilogue writes own h DIRECTLY into hl
//       (LDS); own chunks excluded from poll/deposit (vote 768->720, own
//       publish->read MALL round trip off the local critical path)
//   (b) bank-conflict-free hl layout: row stride 648 elems, member stride 40
//       elems (80B, 16B-aligned) -> deposit banks 4r+20m+3myc (~2-way, free),
//       fragment ds_read_b128 conflict-free per phase
//
//   ws layout (bytes), total ~202.4 MiB:
//     px   @ 0          201,326,592  ([2][512*32][3072] bf16, t-major)
//     whp  @ 201326592   10,485,760  (packed Wh fragments)
//     hxc  @ 211812352      393,216  ([2 layer][2 buf][8 grp][16 m][8 r][6 c]x16B)
//   d_out scratch: phase A xbf/wxt0/wxt1, phase B a1bf (as previous rounds).
// ---------------------------------------------------------------------------

typedef float f32x4 __attribute__((ext_vector_type(4)));
typedef __bf16 bf16x8 __attribute__((ext_vector_type(8)));
typedef unsigned short us8 __attribute__((ext_vector_type(8)));
typedef unsigned short us4 __attribute__((ext_vector_type(4)));
typedef unsigned int u32x4 __attribute__((ext_vector_type(4)));

__device__ __forceinline__ unsigned short f2bf(float f) {
  unsigned int u = __float_as_uint(f);
  u += 0x7FFFu + ((u >> 16) & 1u);            // round-to-nearest-even
  return (unsigned short)(u >> 16);
}
__device__ __forceinline__ float bf2f(unsigned int h) {
  return __uint_as_float(h << 16);
}
__device__ __forceinline__ float sigf(float x) { return 1.0f / (1.0f + __expf(-x)); }
__device__ __forceinline__ float tanh_(float x) { return 2.0f / (1.0f + __expf(-2.0f * x)) - 1.0f; }

#define MFMA(a, b, c) __builtin_amdgcn_mfma_f32_16x16x32_bf16((a), (b), (c), 0, 0, 0)
#define GLOAD_LDS(gp, lp)                                                           \
  __builtin_amdgcn_global_load_lds(                                                 \
      (const __attribute__((address_space(1))) void*)(gp),                          \
      (__attribute__((address_space(3))) void*)(lp), 16, 0, 0)

// Coherent (MALL) 16B chunk load; no waitcnt inside.
__device__ __forceinline__ void chunk1_ld(const char* p, u32x4& v) {
  asm volatile("global_load_dwordx4 %0, %1, off sc0 sc1"
               : "=&v"(v) : "v"(p) : "memory");
}
// Fire-and-forget coherent 16B publish.
__device__ __forceinline__ void pub16(char* p, u32x4 v) {
  asm volatile("global_store_dwordx4 %0, %1, off sc0 sc1" :: "v"(p), "v"(v) : "memory");
}

// --------------------------- prep kernels ----------------------------------

__global__ void k_convert_x(const float* __restrict__ x, unsigned short* __restrict__ xb, int n4) {
  int i = blockIdx.x * blockDim.x + threadIdx.x;
  if (i < n4) {
    float4 v = ((const float4*)x)[i];
    us4 o;
    o[0] = f2bf(v.x); o[1] = f2bf(v.y); o[2] = f2bf(v.z); o[3] = f2bf(v.w);
    ((us4*)xb)[i] = o;
  }
}

// Tiled transpose: WxT[n][k] = bf16(Wx[k][n]); z = layer*2+dir
__global__ __launch_bounds__(256) void k_pack_wxT(
    const float* __restrict__ W0, const float* __restrict__ W1,
    const float* __restrict__ W2, const float* __restrict__ W3,
    unsigned short* __restrict__ o01, unsigned short* __restrict__ o23) {
  int y = blockIdx.z;
  int K = (y >> 1) ? 1024 : 512;
  int kb = blockIdx.y * 32;
  if (kb >= K) return;
  const float* W = (y == 0) ? W0 : (y == 1) ? W1 : (y == 2) ? W2 : W3;
  unsigned short* o = (y >> 1) ? (o23 + (size_t)(y & 1) * 3072 * 1024)
                               : (o01 + (size_t)(y & 1) * 3072 * 512);
  __shared__ float tile[32][33];
  int nb = blockIdx.x * 32;
  int tx = threadIdx.x & 31, ty = threadIdx.x >> 5;   // ty 0..7
#pragma unroll
  for (int r = 0; r < 4; ++r)
    tile[ty + r * 8][tx] = W[(size_t)(kb + ty + r * 8) * 3072 + nb + tx];
  __syncthreads();
#pragma unroll
  for (int r = 0; r < 4; ++r)
    o[(size_t)(nb + ty + r * 8) * K + kb + tx] = f2bf(tile[tx][ty + r * 8]);
}

// Pack Wh (512x2560 f32) into MFMA B-fragments:
// out[(((g*32+ns)*16+ks)*64+lane)*8+e] = Wh[ks*32+(lane>>4)*8+e][g*512+ns*16+(lane&15)]
__global__ void k_pack_whp(const float* __restrict__ W0, const float* __restrict__ W1,
                           const float* __restrict__ W2, const float* __restrict__ W3,
                           unsigned short* __restrict__ out) {
  int y = blockIdx.y;
  const float* W = (y == 0) ? W0 : (y == 1) ? W1 : (y == 2) ? W2 : W3;
  unsigned short* o = out + (size_t)y * 1310720;
  int v = blockIdx.x * 256 + threadIdx.x;   // < 163840
  int lane = v & 63, ks = (v >> 6) & 15, ns = (v >> 10) & 31, g = v >> 15;
  int col = g * 512 + ns * 16 + (lane & 15);
  int kb = ks * 32 + ((lane >> 4) << 3);
  us8 vec;
#pragma unroll
  for (int e = 0; e < 8; ++e) vec[e] = f2bf(W[(size_t)(kb + e) * 2560 + col]);
  *(us8*)&o[(size_t)v * 8] = vec;
}

// --------------------------- bf16 GEMM -------------------------------------
// px[rr][col] with rr = t*32+b (t-major), from A[16384][K] @ Bt[3072][K]^T.
__global__ __launch_bounds__(256) void k_gemm(const unsigned short* __restrict__ A,
                                              const unsigned short* __restrict__ BtBase,
                                              unsigned short* __restrict__ CBase, int K) {
  __shared__ __align__(128) unsigned short As[128 * 32];
  __shared__ __align__(128) unsigned short Bs[128 * 32];
  const unsigned short* Bt = BtBase + (size_t)blockIdx.z * 3072 * K;
  unsigned short* C = CBase + (size_t)blockIdx.z * 16384 * 3072;
  int tid = threadIdx.x;
  int w = tid >> 6, l = tid & 63;
  int m0 = blockIdx.x * 128, n0 = blockIdx.y * 128;
  int wr = (w >> 1) * 64, wc = (w & 1) * 64;
  f32x4 acc[4][4];
#pragma unroll
  for (int i = 0; i < 4; ++i)
#pragma unroll
    for (int j = 0; j < 4; ++j) acc[i][j] = (f32x4){0.f, 0.f, 0.f, 0.f};

  for (int k0 = 0; k0 < K; k0 += 32) {
    __syncthreads();
#pragma unroll
    for (int half = 0; half < 2; ++half) {
      int r = w * 32 + half * 16 + (l >> 2);     // row within tile
      int gq = (l & 3) ^ (r & 3);                // swizzled source quarter
      GLOAD_LDS(A + (size_t)(m0 + r) * K + k0 + gq * 8, &As[(w * 32 + half * 16) * 32]);
      GLOAD_LDS(Bt + (size_t)(n0 + r) * K + k0 + gq * 8, &Bs[(w * 32 + half * 16) * 32]);
    }
    __syncthreads();
    bf16x8 af[4], bfr[4];
#pragma unroll
    for (int mi = 0; mi < 4; ++mi) {
      int r = wr + mi * 16 + (l & 15);
      int q = (l >> 4) ^ (r & 3);
      af[mi] = __builtin_bit_cast(bf16x8, *(const us8*)&As[r * 32 + q * 8]);
    }
#pragma unroll
    for (int ni = 0; ni < 4; ++ni) {
      int r = wc + ni * 16 + (l & 15);
      int q = (l >> 4) ^ (r & 3);
      bfr[ni] = __builtin_bit_cast(bf16x8, *(const us8*)&Bs[r * 32 + q * 8]);
    }
#pragma unroll
    for (int mi = 0; mi < 4; ++mi)
#pragma unroll
      for (int ni = 0; ni < 4; ++ni) acc[mi][ni] = MFMA(af[mi], bfr[ni], acc[mi][ni]);
  }
#pragma unroll
  for (int mi = 0; mi < 4; ++mi)
#pragma unroll
    for (int ni = 0; ni < 4; ++ni)
#pragma unroll
      for (int r4 = 0; r4 < 4; ++r4) {
        int row = m0 + wr + mi * 16 + (l >> 4) * 4 + r4;    // b*512 + t
        int rr = ((row & 511) << 5) + (row >> 9);           // t*32 + b
        int col = n0 + wc + ni * 16 + (l & 15);
        C[(size_t)rr * 3072 + col] = f2bf(acc[mi][ni][r4]);
      }
}

// --------------------------- persistent LSTM layer -------------------------
// 128 WGs x 512 threads = 8 groups (dir d, batch-quarter q) x 16 members.
// Member m owns hidden units m*32..m*32+31. 8 waves: kh = w&3 (K quarter),
// nh = w>>2 (hidden half); wf[5][4] = 80 VGPR/wave, register-resident.
// Exchange: 768 chunks/group {6 bf16 | enc(s)}; OWN member's 48 chunks are
// written directly to LDS at epilogue (no MALL roundtrip); foreign chunks
// partition-polled 1-2/thread and deposited into hl.
// hl layout: [8 rows][16 membs x 40 elems, row stride 648] (bank-tuned).
__global__ __launch_bounds__(512, 1) void k_persist(
    const unsigned short* __restrict__ px,    // [2][512*32][3072] bf16 t-major
    const unsigned short* __restrict__ wp,    // this layer's packed Wh (2 dirs)
    const float* __restrict__ bias_f, const float* __restrict__ bias_b,
    char* __restrict__ hxc,                   // [2 layer][2 buf][8 grp][16 m][8 r][6 c]x16B
    unsigned short* __restrict__ ybf,         // layer0: a1bf, else null
    float* __restrict__ yf,                   // layer1: d_out, else null
    float* __restrict__ finals,               // d_out + 16777216
    int layer) {
  __shared__ float part[2][4][8][160];        // 40 KiB, parity-buffered
  __shared__ unsigned short hl[8 * 648];      // 10.125 KiB h image (bank-tuned)
  int wg = blockIdx.x;
  int grp = wg >> 4, m = wg & 15;
  int d = grp & 1, q = grp >> 1;
  int tid = threadIdx.x;
  int w = tid >> 6, l = tid & 63;
  int kh = w & 3, nh = w >> 2;
  int ns = m * 2 + nh;                        // 16-hidden slice id (0..31)
  const unsigned short* wpd = wp + (size_t)d * 1310720;
  const unsigned short* pxd = px + (size_t)d * 16384 * 3072;
  const float* bias = d ? bias_b : bias_f;
  char* hxg = hxc + (size_t)layer * 196608 + (size_t)grp * 12288;

  // ---- Wh fragments register-resident: wf[gate][kk], this wave's K-quarter
  bf16x8 wf[5][4];
#pragma unroll
  for (int g5 = 0; g5 < 5; ++g5)
#pragma unroll
    for (int kk = 0; kk < 4; ++kk)
      wf[g5][kk] = __builtin_bit_cast(
          bf16x8,
          *(const us8*)&wpd[(size_t)((g5 * 32 + ns) * 16 + (kh * 4 + kk)) * 512 + l * 8]);

  // ---- epilogue constants (threads 0..255 = waves 0..3) ----
  bool epi = tid < 256;
  int r = tid >> 5, j = tid & 31, jg = m * 32 + j, b = q * 8 + r;
  float bv[5];
#pragma unroll
  for (int g5 = 0; g5 < 5; ++g5) bv[g5] = bias[(g5 << 9) + jg];

  float c = 0.f;
  unsigned int xCur[6], xNext[6];             // px register double-buffer
  if (epi) {
    int t0 = d ? 511 : 0;
    const unsigned short* pp = pxd + ((size_t)((t0 << 5) + b)) * 3072 + jg;
#pragma unroll
    for (int q6 = 0; q6 < 6; ++q6) xNext[q6] = pp[q6 << 9];
  }

  // ---- partition-poll assignment: chunks c0 = tid, c1 = 512+tid (tid<256)
  int c0 = tid;
  int c1 = 512 + tid;
  bool has1 = tid < 256;
  int m8r0 = c0 / 6, myc0 = c0 - m8r0 * 6;
  bool own0 = (c0 / 48) == m;                 // own member's chunk
  int off0 = (m8r0 & 7) * 648 + (m8r0 >> 3) * 40 + myc0 * 6;   // elems
  bool is5_0 = (myc0 == 5);
  int m8r1 = c1 / 6, myc1 = c1 - m8r1 * 6;
  bool own1 = (c1 / 48) == m;
  int off1 = (m8r1 & 7) * 648 + (m8r1 >> 3) * 40 + myc1 * 6;
  bool is5_1 = (myc1 == 5);

  int myc = l & 31, pbase = l & 32, prow = 2 * w + (l >> 5);  // publish (waves 0..3)

  for (int s = 0; s < 512; ++s) {
    int t = d ? (511 - s) : s;

    // ---- partition-poll + LDS deposit (foreign chunks only; skip s=0) ----
    if (s > 0) {
      const char* cb = hxg + (size_t)(s & 1) * 98304;
      const char* a0 = cb + (size_t)c0 * 16;
      const char* a1 = cb + (size_t)c1 * 16;
      unsigned enc = (unsigned)(s | ((~s & 0xFFFF) << 16));
      u32x4 v0, v1;
      bool d0 = own0, d1 = !has1 || own1;
      long guard = 0;
      bool first = true, ok;
      do {
        if (!first) __builtin_amdgcn_s_sleep(1);   // throttle retry traffic
        first = false;
        if (!d0) chunk1_ld(a0, v0);
        if (!d1) chunk1_ld(a1, v1);
        asm volatile("s_waitcnt vmcnt(0)" ::: "memory");
        __builtin_amdgcn_sched_barrier(0);
        d0 = d0 || (v0[3] == enc);
        d1 = d1 || (v1[3] == enc);
        ok = (__all((int)(d0 && d1)) != 0);
      } while (!ok && ++guard < 300000L);
      // deposit foreign payloads (dword-aligned LDS writes)
      if (!own0) {
        unsigned int* pw = (unsigned int*)((char*)hl + off0 * 2);
        pw[0] = v0[0];
        if (!is5_0) { pw[1] = v0[1]; pw[2] = v0[2]; }
      }
      if (has1 && !own1) {
        unsigned int* pw1 = (unsigned int*)((char*)hl + off1 * 2);
        pw1[0] = v1[0];
        if (!is5_1) { pw1[1] = v1[1]; pw1[2] = v1[2]; }
      }
    }

    // ---- px: promote prefetch, issue next (compiler-managed waits) ----
    if (epi) {
#pragma unroll
      for (int i = 0; i < 6; ++i) xCur[i] = xNext[i];   // loads are 1 iter old
      if (s < 511) {
        int tn = d ? (511 - (s + 1)) : (s + 1);
        const unsigned short* pp = pxd + ((size_t)((tn << 5) + b)) * 3072 + jg;
#pragma unroll
        for (int q6 = 0; q6 < 6; ++q6) xNext[q6] = pp[q6 << 9];
      }
    }

    __syncthreads();                          // B1: hl image complete

    // ---- MFMA: M=8(pad16) x N=80 x K=128 per wave, A-frags from LDS ----
    f32x4 acc[5];
#pragma unroll
    for (int g5 = 0; g5 < 5; ++g5) acc[g5] = (f32x4){0.f, 0.f, 0.f, 0.f};
    if (s > 0) {
#pragma unroll
      for (int kk = 0; kk < 4; ++kk) {
        bf16x8 av = __builtin_bit_cast(
            bf16x8,
            *(const us8*)&hl[(l & 7) * 648 + (4 * kh + kk) * 40 + ((l >> 4) << 3)]);
#pragma unroll
        for (int g5 = 0; g5 < 5; ++g5) acc[g5] = MFMA(av, wf[g5][kk], acc[g5]);
      }
    }
    if (l < 32) {
#pragma unroll
      for (int g5 = 0; g5 < 5; ++g5)
#pragma unroll
        for (int r4 = 0; r4 < 4; ++r4)
          part[s & 1][kh][(l >> 4) * 4 + r4][nh * 80 + g5 * 16 + (l & 15)] = acc[g5][r4];
    }
    __syncthreads();                          // B2: part ready

    // ---- epilogue + publish (threads 0..255) ----
    if (epi) {
      int cc0 = (j >> 4) * 80 + (j & 15);
      float ps_[5];
#pragma unroll
      for (int g5 = 0; g5 < 5; ++g5) {
        int cc = cc0 + g5 * 16;
        ps_[g5] = part[s & 1][0][r][cc] + part[s & 1][1][r][cc] +
                  part[s & 1][2][r][cc] + part[s & 1][3][r][cc] + bv[g5];
      }
      float x0 = bf2f(xCur[0]), x1 = bf2f(xCur[1]), x2 = bf2f(xCur[2]);
      float x3 = bf2f(xCur[3]), x4 = bf2f(xCur[4]), x5 = bf2f(xCur[5]);
      float iG = sigf(x0 + ps_[0]);
      float fG = sigf(x1 + ps_[1]);
      float gG = tanh_(x2 + ps_[2]);
      float oG = sigf(x3 + ps_[3]);
      float cn = iG * gG + fG * c;
      c = cn;
      float ht = oG * tanh_(cn);
      float rG = sigf(x4 + ps_[4]);
      ht = rG * ht + (1.f - rG) * x5;

      // publish FIRST (foreign members' next-step critical path)
      unsigned short hb16 = f2bf(ht);
      if (s < 511) {
        unsigned int hbits = (unsigned int)hb16;
        unsigned int vv[6];
#pragma unroll
        for (int i = 0; i < 6; ++i)
          vv[i] = __shfl(hbits, (pbase + myc * 6 + i) & 63);
        unsigned int pw0 = vv[0] | (vv[1] << 16);
        unsigned int pw1 = vv[2] | (vv[3] << 16);
        unsigned int pw2 = vv[4] | (vv[5] << 16);
        if (myc == 5) { pw1 = 0; pw2 = 0; }
        if (myc < 6) {
          char* dst = hxg + (size_t)((s + 1) & 1) * 98304 +
                      (size_t)((m * 8 + prow) * 6 + myc) * 16;
          unsigned enc1 = (unsigned)((s + 1) | ((~(s + 1) & 0xFFFF) << 16));
          u32x4 pv = {pw0, pw1, pw2, enc1};
          pub16(dst, pv);
        }
        // own-member short-circuit: next step's hl comes straight from LDS
        hl[r * 648 + m * 40 + j] = hb16;
      }

      size_t yo = ((size_t)(b * 512 + t)) * 1024 + d * 512 + jg;
      if (ybf) ybf[yo] = hb16;
      else     yf[yo] = ht;
      if (s == 511) {
        int fo = (layer * 32 + b) * 1024 + d * 512 + jg;
        finals[fo] = ht;            // final_h
        finals[65536 + fo] = cn;    // final_c
      }
    }
  }
}

// --------------------------- host ------------------------------------------

extern "C" void kernel_launch(void* const* d_in, const int* in_sizes, int n_in,
                              void* d_out, int out_size, void* d_ws, size_t ws_size,
                              hipStream_t stream) {
  (void)in_sizes; (void)n_in; (void)out_size; (void)ws_size;
  const float* x = (const float*)d_in[0];
  const float* Wx[4] = {(const float*)d_in[1], (const float*)d_in[4],
                        (const float*)d_in[7], (const float*)d_in[10]};
  const float* Wh[4] = {(const float*)d_in[2], (const float*)d_in[5],
                        (const float*)d_in[8], (const float*)d_in[11]};
  const float* bs[4] = {(const float*)d_in[3], (const float*)d_in[6],
                        (const float*)d_in[9], (const float*)d_in[12]};

  // ws: px + packed Wh + chunk exchange (~202.4 MiB)
  char* ws = (char*)d_ws;
  unsigned short* px   = (unsigned short*)(ws);
  unsigned short* whp  = (unsigned short*)(ws + 201326592);
  char*           hxc  = (char*)(ws + 211812352);

  // d_out doubles as scratch for transients (all dead before final y writes)
  char* ob = (char*)d_out;
  unsigned short* xbf  = (unsigned short*)(ob);             // 16 MiB, phase A
  unsigned short* wxt0 = (unsigned short*)(ob + 16777216);  // 6 MiB, phase A
  unsigned short* wxt1 = (unsigned short*)(ob + 33554432);  // 12 MiB
  unsigned short* a1bf = (unsigned short*)(ob);             // 32 MiB, phase B
  float* out = (float*)d_out;
  float* finals = out + 16777216;

  k_convert_x<<<8192, 256, 0, stream>>>(x, xbf, 2097152);
  k_pack_wxT<<<dim3(96, 32, 4), 256, 0, stream>>>(Wx[0], Wx[1], Wx[2], Wx[3], wxt0, wxt1);
  k_pack_whp<<<dim3(640, 4), 256, 0, stream>>>(Wh[0], Wh[1], Wh[2], Wh[3], whp);
  hipMemsetAsync(hxc, 0xFF, 393216, stream);   // never decodes as a valid seq

  for (int layer = 0; layer < 2; ++layer) {
    int K = layer ? 1024 : 512;
    const unsigned short* Ag = layer ? a1bf : xbf;
    const unsigned short* wxt = layer ? wxt1 : wxt0;
    k_gemm<<<dim3(128, 24, 2), 256, 0, stream>>>(Ag, wxt, px, K);
    k_persist<<<128, 512, 0, stream>>>(
        px, whp + (size_t)layer * 2621440, bs[layer * 2], bs[layer * 2 + 1],
        hxc, layer ? nullptr : a1bf, layer ? out : nullptr, finals, layer);
  }
}